// Round 1
// 292.075 us; speedup vs baseline: 1.0044x; 1.0044x over previous
//
#include <hip/hip_runtime.h>
#include <hip/hip_bf16.h>

#define TSEQ  4096
#define NBATCH 4
#define CDIM  2048
#define DH    128

typedef __bf16 bf16x8 __attribute__((ext_vector_type(8)));
typedef float  f32x4  __attribute__((ext_vector_type(4)));
typedef unsigned short u16x8 __attribute__((ext_vector_type(8)));
typedef unsigned       u32x4 __attribute__((ext_vector_type(4)));
typedef unsigned short u16;

__device__ __forceinline__ u16 f2bf(float f) {
  union { float f; unsigned u; } v; v.f = f;
  unsigned r = (v.u + 0x7FFFu + ((v.u >> 16) & 1u)) >> 16;
  return (u16)r;
}
__device__ __forceinline__ float bf2f(u16 h) {
  union { unsigned u; float f; } v; v.u = ((unsigned)h) << 16;
  return v.f;
}
__device__ __forceinline__ bf16x8 ld_bf8(const u16* p) {
  return __builtin_bit_cast(bf16x8, *(const u16x8*)p);
}
__device__ __forceinline__ unsigned pk2(float lo, float hi) {
  float2 f; f.x = lo; f.y = hi;
  __hip_bfloat162 h = __float22bfloat162_rn(f);
  unsigned r; __builtin_memcpy(&r, &h, 4);
  return r;
}
__device__ __forceinline__ u16x8 cvt8u(float4 a, float4 b) {
  u32x4 u;
  u[0] = pk2(a.x, a.y); u[1] = pk2(a.z, a.w);
  u[2] = pk2(b.x, b.y); u[3] = pk2(b.z, b.w);
  return __builtin_bit_cast(u16x8, u);
}

// raw workgroup barrier: drains LDS (lgkmcnt) only, NOT vmcnt — keeps global
// prefetch loads in flight across the barrier (hipcc's __syncthreads emits
// s_waitcnt vmcnt(0) which defeats software pipelining).
__device__ __forceinline__ void lds_barrier() {
  asm volatile("s_waitcnt lgkmcnt(0)" ::: "memory");
  __builtin_amdgcn_s_barrier();
}

// DPP cross-lane (VALU pipe): reduce over each 16-lane row
template<int CTRL>
__device__ __forceinline__ float dppmv(float x) {
  return __builtin_bit_cast(float,
    __builtin_amdgcn_update_dpp(0, __builtin_bit_cast(int, x), CTRL, 0xF, 0xF, true));
}
__device__ __forceinline__ float red_max16(float v) {
  v = fmaxf(v, dppmv<0xB1>(v));
  v = fmaxf(v, dppmv<0x4E>(v));
  v = fmaxf(v, dppmv<0x124>(v));
  v = fmaxf(v, dppmv<0x128>(v));
  return v;
}
__device__ __forceinline__ float red_sum16(float v) {
  v += dppmv<0xB1>(v);
  v += dppmv<0x4E>(v);
  v += dppmv<0x124>(v);
  v += dppmv<0x128>(v);
  return v;
}

// unit base within a batch: q-tile Q (128 rows) has (Q>>2)+1 chunks
__device__ __forceinline__ int unit_base(int Q) {
  int a = Q >> 2, bq = Q & 3;
  return 2 * a * (a + 1) + bq * (a + 1);
}

// ---------------- fused prep: vt | wconv | ropek in one launch ----------------
// vt blocks (heaviest: LDS transpose) go FIRST to cut the dispatch tail.
__global__ __launch_bounds__(256) void k_prep(const float* __restrict__ w, u16* __restrict__ wbf,
                                              const float* __restrict__ key, u16* __restrict__ krot,
                                              const float* __restrict__ value, u16* __restrict__ vt) {
  __shared__ u16 S[128 * 66];
  int bid = blockIdx.x;
  int tid = threadIdx.x;
  if (bid < 256) {
    // value transpose [B,T,D] -> [B,D,T] in bf16
    int vb = bid;
    int b = vb >> 6;
    int t0 = (vb & 63) * 64;
    int d = (tid & 31) * 4;
    int tl0 = tid >> 5;
#pragma unroll
    for (int i = 0; i < 8; ++i) {
      int tl = tl0 + i * 8;
      const float4 val = *(const float4*)(value + ((size_t)(b * TSEQ + t0 + tl)) * DH + d);
      S[(d + 0) * 66 + tl] = f2bf(val.x);
      S[(d + 1) * 66 + tl] = f2bf(val.y);
      S[(d + 2) * 66 + tl] = f2bf(val.z);
      S[(d + 3) * 66 + tl] = f2bf(val.w);
    }
    __syncthreads();
#pragma unroll
    for (int i = 0; i < 16; ++i) {
      int idx = tid + i * 256;
      int dd = idx >> 5;
      int tw = (idx & 31) * 2;
      unsigned lo = S[dd * 66 + tw];
      unsigned hi = S[dd * 66 + tw + 1];
      *(unsigned*)(vt + ((size_t)(b * DH + dd)) * TSEQ + t0 + tw) = lo | (hi << 16);
    }
  } else if (bid < 512) {
    // w_q fp32 -> bf16
    int i = (bid - 256) * 256 + tid;
    const float4 v = *(const float4*)(w + (size_t)i * 4);
    uint2 o; o.x = pk2(v.x, v.y); o.y = pk2(v.z, v.w);
    *(uint2*)(wbf + (size_t)i * 4) = o;
  } else {
    // RoPE on key, fp32 -> bf16
    int g = (bid - 512) * 256 + tid;
    int p = g & 63;
    int row = g >> 6;
    int t = row & (TSEQ - 1);
    const float2 kv = *(const float2*)(key + (size_t)row * DH + 2 * p);
    float inv = powf(10000.0f, -(float)p / 64.0f);
    float ang = (float)t * inv;
    float s, c; sincosf(ang, &s, &c);
    *(unsigned*)(krot + (size_t)row * DH + 2 * p) = pk2(kv.x * c - kv.y * s, kv.x * s + kv.y * c);
  }
}

// ------- q projection: bf16 frag-major LDS tile, BK=128, 32-row tiles, fused RoPE -------
// 2-deep register ping-pong prefetch (paA/paB, static indexing) + raw lgkm-only
// barriers so the it+2 HBM load stays in flight across both barriers (~2 full
// iterations of cover vs ~1 MFMA phase before). Trig computed inline in the
// epilogue (identical formula to the old ct/st tables -> bit-identical output).
__global__ __launch_bounds__(256, 2) void k_qproj(const float* __restrict__ x,
                                                  const u16* __restrict__ wbf,
                                                  u16* __restrict__ qrot) {
  __shared__ u16 Al[16 * 32 * 8];        // 8 KB, [chunk][row][8]
  int bid = blockIdx.x;
  int tid = threadIdx.x;
  int w = tid >> 6;
  int lane = tid & 63;
  int l15 = lane & 15;
  int quad = lane >> 4;
  int m0 = bid * 32;

  int srow = tid >> 3;                   // 0..31
  int c16 = (tid & 7) * 16;              // col offset 0..112
  int chunk0 = (tid & 7) * 2;
  const float* xg = x + (size_t)(m0 + srow) * CDIM + c16;

  f32x4 acc[2][2];
#pragma unroll
  for (int mt = 0; mt < 2; ++mt)
#pragma unroll
    for (int nt = 0; nt < 2; ++nt) acc[mt][nt] = (f32x4){0.f, 0.f, 0.f, 0.f};

  float4 paA[4], paB[4];
#pragma unroll
  for (int i = 0; i < 4; ++i) paA[i] = *(const float4*)(xg + i * 4);
#pragma unroll
  for (int i = 0; i < 4; ++i) paB[i] = *(const float4*)(xg + 128 + i * 4);

  auto qstep = [&](float4 (&pa)[4], int itc) {
    u16x8 lo = cvt8u(pa[0], pa[1]);
    u16x8 hi = cvt8u(pa[2], pa[3]);
    if (itc + 2 < CDIM / 128) {          // prefetch it+2 into the buffer just consumed
      const float* xn = xg + (size_t)(itc + 2) * 128;
#pragma unroll
      for (int i = 0; i < 4; ++i) pa[i] = *(const float4*)(xn + i * 4);
    }
    lds_barrier();
    *(u16x8*)&Al[(chunk0 * 32 + srow) * 8] = lo;
    *(u16x8*)&Al[((chunk0 + 1) * 32 + srow) * 8] = hi;
    lds_barrier();
    int k0 = itc * 128;
#pragma unroll
    for (int ks = 0; ks < 4; ++ks) {
      bf16x8 af[2];
#pragma unroll
      for (int mt = 0; mt < 2; ++mt)
        af[mt] = ld_bf8(&Al[(((ks * 4 + quad) * 32) + mt * 16 + l15) * 8]);
#pragma unroll
      for (int nt = 0; nt < 2; ++nt) {
        bf16x8 bfrag = ld_bf8(wbf + (size_t)(w * 32 + nt * 16 + l15) * CDIM + k0 + ks * 32 + quad * 8);
#pragma unroll
        for (int mt = 0; mt < 2; ++mt)
          acc[mt][nt] = __builtin_amdgcn_mfma_f32_16x16x32_bf16(af[mt], bfrag, acc[mt][nt], 0, 0, 0);
      }
    }
  };

#pragma unroll 1
  for (int ith = 0; ith < 8; ++ith) {
    qstep(paA, 2 * ith);
    qstep(paB, 2 * ith + 1);
  }

  const float scale = 0.08838834764831845f;  // 128^-0.5
#pragma unroll
  for (int nt = 0; nt < 2; ++nt) {
    int dcol = w * 32 + nt * 16 + l15;
    int p = dcol >> 1;
    float inv = powf(10000.0f, -(float)p / 64.0f);
#pragma unroll
    for (int mt = 0; mt < 2; ++mt) {
#pragma unroll
      for (int r = 0; r < 4; ++r) {
        int m = m0 + mt * 16 + quad * 4 + r;
        int t = m & (TSEQ - 1);
        float ang = (float)t * inv;
        float s, c; sincosf(ang, &s, &c);
        float val = acc[mt][nt][r];
        float partner = __shfl_xor(val, 1, 64);
        float o = (lane & 1) ? (val * c + partner * s) : (val * c - partner * s);
        qrot[(size_t)m * DH + dcol] = f2bf(o * scale);
      }
    }
  }
}

// ------- causal flash attention: units = (b, 128-row q-tile, <=8 k-tiles of 64 keys) -------
__global__ __launch_bounds__(256, 2) void k_attn(const u16* __restrict__ qrot,
                                                 const u16* __restrict__ krot,
                                                 const u16* __restrict__ vt,
                                                 u16* __restrict__ Opart,
                                                 float2* __restrict__ ml) {
  __shared__ u16 Kl[16 * 64 * 8];
  __shared__ u16 Vl[8 * 128 * 8];
  __shared__ u16 Pl[4 * 32 * 72];

  int bid = blockIdx.x;                // 576 = 4 * 144
  int b = bid / 144;
  int u = bid - b * 144;
  int Q = 0;
#pragma unroll 1
  for (int q = 31; q >= 0; --q) {
    if (unit_base(q) <= u) { Q = q; break; }
  }
  int kc = u - unit_base(Q);
  int nkt = 2 * Q + 2;
  int kt0 = kc * 8;
  int kt1 = min(kt0 + 8, nkt);
  int m0 = Q * 128;

  int tid = threadIdx.x;
  int w = tid >> 6;
  int lane = tid & 63;
  int l15 = lane & 15;
  int quad = lane >> 4;
  u16* pw = Pl + w * 32 * 72;

  int rK = tid & 63;   int jgK = tid >> 6;
  int dV = tid & 127;  int hV = tid >> 7;

  const u16* kb = krot + (size_t)b * TSEQ * DH;
  const u16* vb = vt + (size_t)b * DH * TSEQ;

  bf16x8 qf[2][4];
#pragma unroll
  for (int mt = 0; mt < 2; ++mt) {
    const u16* qb = qrot + ((size_t)(b * TSEQ + m0 + mt * 64 + w * 16 + l15)) * DH + quad * 8;
#pragma unroll
    for (int c = 0; c < 4; ++c) qf[mt][c] = ld_bf8(qb + c * 32);
  }

  f32x4 o_acc[2][8];
#pragma unroll
  for (int mt = 0; mt < 2; ++mt)
#pragma unroll
    for (int i = 0; i < 8; ++i) o_acc[mt][i] = (f32x4){0.f, 0.f, 0.f, 0.f};
  float m_st[2][4], l_st[2][4];
#pragma unroll
  for (int mt = 0; mt < 2; ++mt)
#pragma unroll
    for (int r = 0; r < 4; ++r) { m_st[mt][r] = -INFINITY; l_st[mt][r] = 0.f; }

  u16x8 kr[4], vr[4];
  {
    const u16* ks = kb + (size_t)(kt0 * 64 + rK) * DH + jgK * 32;
    const u16* vs = vb + (size_t)dV * TSEQ + kt0 * 64 + hV * 32;
#pragma unroll
    for (int i = 0; i < 4; ++i) { kr[i] = *(const u16x8*)(ks + i * 8); vr[i] = *(const u16x8*)(vs + i * 8); }
  }

  for (int kt = kt0; kt < kt1; ++kt) {
    lds_barrier();
#pragma unroll
    for (int i = 0; i < 4; ++i) {
      *(u16x8*)&Kl[((jgK * 4 + i) * 64 + rK) * 8] = kr[i];
      *(u16x8*)&Vl[((hV * 4 + i) * 128 + dV) * 8] = vr[i];
    }
    lds_barrier();
    if (kt + 1 < kt1) {
      const u16* ks = kb + (size_t)((kt + 1) * 64 + rK) * DH + jgK * 32;
      const u16* vs = vb + (size_t)dV * TSEQ + (kt + 1) * 64 + hV * 32;
#pragma unroll
      for (int i = 0; i < 4; ++i) { kr[i] = *(const u16x8*)(ks + i * 8); vr[i] = *(const u16x8*)(vs + i * 8); }
    }

    f32x4 s[2][4];
#pragma unroll
    for (int mt = 0; mt < 2; ++mt)
#pragma unroll
      for (int nt = 0; nt < 4; ++nt) s[mt][nt] = (f32x4){0.f, 0.f, 0.f, 0.f};
    __builtin_amdgcn_s_setprio(1);
#pragma unroll
    for (int c = 0; c < 4; ++c)
#pragma unroll
      for (int nt = 0; nt < 4; ++nt) {
        bf16x8 kf = ld_bf8(&Kl[((c * 4 + quad) * 64 + nt * 16 + l15) * 8]);
#pragma unroll
        for (int mt = 0; mt < 2; ++mt)
          s[mt][nt] = __builtin_amdgcn_mfma_f32_16x16x32_bf16(qf[mt][c], kf, s[mt][nt], 0, 0, 0);
      }
    __builtin_amdgcn_s_setprio(0);

    if (kt * 64 >= m0) {
#pragma unroll
      for (int mt = 0; mt < 2; ++mt)
#pragma unroll
        for (int nt = 0; nt < 4; ++nt)
#pragma unroll
          for (int r = 0; r < 4; ++r) {
            int key_g = kt * 64 + nt * 16 + l15;
            int row_g = m0 + mt * 64 + w * 16 + quad * 4 + r;
            if (key_g > row_g) s[mt][nt][r] = -INFINITY;
          }
    }

    float alpha[2][4];
    int chg = 0;
#pragma unroll
    for (int mt = 0; mt < 2; ++mt)
#pragma unroll
      for (int r = 0; r < 4; ++r) {
        float rm = fmaxf(fmaxf(s[mt][0][r], s[mt][1][r]), fmaxf(s[mt][2][r], s[mt][3][r]));
        rm = red_max16(rm);
        float mn = fmaxf(m_st[mt][r], rm);
        float al = __expf(m_st[mt][r] - mn);
        m_st[mt][r] = mn;
        float ps = 0.f;
#pragma unroll
        for (int nt = 0; nt < 4; ++nt) {
          float pv = __expf(s[mt][nt][r] - mn);
          s[mt][nt][r] = pv;
          ps += pv;
        }
        ps = red_sum16(ps);
        l_st[mt][r] = l_st[mt][r] * al + ps;
        alpha[mt][r] = al;
        chg |= (al != 1.0f);
      }
    if (__any(chg)) {
#pragma unroll
      for (int mt = 0; mt < 2; ++mt)
#pragma unroll
        for (int nt = 0; nt < 8; ++nt)
#pragma unroll
          for (int r = 0; r < 4; ++r) o_acc[mt][nt][r] *= alpha[mt][r];
    }

#pragma unroll
    for (int mt = 0; mt < 2; ++mt)
#pragma unroll
      for (int nt = 0; nt < 4; ++nt)
#pragma unroll
        for (int r = 0; r < 4; ++r)
          pw[(mt * 16 + quad * 4 + r) * 72 + nt * 16 + l15] = f2bf(s[mt][nt][r]);

#pragma unroll
    for (int c2 = 0; c2 < 2; ++c2) {
      bf16x8 pf[2];
#pragma unroll
      for (int mt = 0; mt < 2; ++mt)
        pf[mt] = ld_bf8(pw + (mt * 16 + l15) * 72 + c2 * 32 + quad * 8);
      __builtin_amdgcn_s_setprio(1);
#pragma unroll
      for (int nt = 0; nt < 8; ++nt) {
        bf16x8 vf = ld_bf8(&Vl[((c2 * 4 + quad) * 128 + nt * 16 + l15) * 8]);
#pragma unroll
        for (int mt = 0; mt < 2; ++mt)
          o_acc[mt][nt] = __builtin_amdgcn_mfma_f32_16x16x32_bf16(pf[mt], vf, o_acc[mt][nt], 0, 0, 0);
      }
      __builtin_amdgcn_s_setprio(0);
    }
  }

  u16* op = Opart + (size_t)bid * (128 * 128);
#pragma unroll
  for (int mt = 0; mt < 2; ++mt)
#pragma unroll
    for (int nt = 0; nt < 8; ++nt)
#pragma unroll
      for (int r = 0; r < 4; ++r)
        op[(mt * 64 + w * 16 + quad * 4 + r) * 128 + nt * 16 + l15] = f2bf(o_acc[mt][nt][r]);
  if (l15 == 0) {
#pragma unroll
    for (int mt = 0; mt < 2; ++mt)
#pragma unroll
      for (int r = 0; r < 4; ++r) {
        float2 p; p.x = m_st[mt][r]; p.y = l_st[mt][r];
        ml[(size_t)bid * 128 + mt * 64 + w * 16 + quad * 4 + r] = p;
      }
  }
}

// ------- merge partials: one block per (b, 128-row q-tile), vectorized -------
__global__ __launch_bounds__(256) void k_merge(const u16* __restrict__ Opart,
                                               const float2* __restrict__ ml,
                                               float* __restrict__ out) {
  __shared__ float wgt[8][128];
  __shared__ float invL[128];
  int bid = blockIdx.x;                // b*32 + Q
  int b = bid >> 5, Q = bid & 31;
  int C = (Q >> 2) + 1;
  int base = b * 144 + unit_base(Q);
  int tid = threadIdx.x;
  if (tid < 128) {
    float mv[8], lv[8];
    float M = -INFINITY;
    for (int c = 0; c < C; ++c) {
      float2 p = ml[(size_t)(base + c) * 128 + tid];
      mv[c] = p.x; lv[c] = p.y;
      M = fmaxf(M, p.x);
    }
    float L = 0.f;
    for (int c = 0; c < C; ++c) {
      float wv = __expf(mv[c] - M);
      wgt[c][tid] = wv;
      L += wv * lv[c];
    }
    invL[tid] = 1.f / L;
  }
  __syncthreads();
#pragma unroll
  for (int k = 0; k < 8; ++k) {
    int slot = tid + k * 256;          // 2048 slots of 8 elems (128x128)
    int row = slot >> 4;
    float acc[8];
#pragma unroll
    for (int j = 0; j < 8; ++j) acc[j] = 0.f;
    for (int c = 0; c < C; ++c) {
      u16x8 v = *(const u16x8*)&Opart[(size_t)(base + c) * (128 * 128) + slot * 8];
      float wv = wgt[c][row];
#pragma unroll
      for (int j = 0; j < 8; ++j) acc[j] += wv * bf2f(v[j]);
    }
    float il = invL[row];
    float4 o0, o1;
    o0.x = acc[0] * il; o0.y = acc[1] * il; o0.z = acc[2] * il; o0.w = acc[3] * il;
    o1.x = acc[4] * il; o1.y = acc[5] * il; o1.z = acc[6] * il; o1.w = acc[7] * il;
    float* op = out + ((size_t)(b * TSEQ + Q * 128 + row)) * DH + (slot & 15) * 8;
    *(float4*)op = o0;
    *(float4*)(op + 4) = o1;
  }
}

extern "C" void kernel_launch(void* const* d_in, const int* in_sizes, int n_in,
                              void* d_out, int out_size, void* d_ws, size_t ws_size,
                              hipStream_t stream) {
  const float* x     = (const float*)d_in[0];
  const float* key   = (const float*)d_in[1];
  const float* value = (const float*)d_in[2];
  const float* w_q   = (const float*)d_in[3];
  float* out = (float*)d_out;

  char* ws = (char*)d_ws;
  u16* wbf    = (u16*)(ws);                    // 512 KB
  u16* qrot   = (u16*)(ws + (1u  << 20));      // 4 MB
  u16* krot   = (u16*)(ws + (5u  << 20));      // 4 MB
  u16* vt     = (u16*)(ws + (9u  << 20));      // 4 MB
  u16* Opart  = (u16*)(ws + (13u << 20));      // 18.87 MB
  float2* ml  = (float2*)(ws + (32u << 20));   // 590 KB

  k_prep<<<4608, 256, 0, stream>>>(w_q, wbf, key, krot, value, vt);
  k_qproj<<<(NBATCH * TSEQ) / 32, 256, 0, stream>>>(x, wbf, qrot);
  k_attn<<<NBATCH * 144, 256, 0, stream>>>(qrot, krot, vt, Opart, ml);
  k_merge<<<NBATCH * 32, 256, 0, stream>>>(Opart, ml, out);
}